// Round 4
// baseline (11385.200 us; speedup 1.0000x reference)
//
#include <hip/hip_runtime.h>
#include <hip/hip_bf16.h>
#include <hip/hip_cooperative_groups.h>
#include <cstdio>

namespace cg = cooperative_groups;

#define NBATCH 64
#define TSTEPS 512
#define DDIM   1024
#define HDIM   1024
#define ACOLS  4096
#define NBLK   256
#define NTHR   256
#define HCB    4        // h-cols per block -> 16 a-cols
#define KPX    1032     // LDS k-stride: start-bank groups land 8 lanes / 4-bank group (balanced for b128)

typedef __attribute__((ext_vector_type(8))) short bf16x8;
typedef __attribute__((ext_vector_type(4))) float f32x4;
typedef unsigned int  u32;
typedef unsigned short u16;
typedef unsigned long long u64;

__device__ __forceinline__ u16 bf_hi(float f) { __hip_bfloat16 h = __float2bfloat16(f); return *(u16*)&h; }
__device__ __forceinline__ float bf2f(u16 u)  { __hip_bfloat16 h = *(__hip_bfloat16*)&u; return __bfloat162float(h); }

// h fragment-plane indexing: element (row n, col k) ->
//   w=n>>4, r=n&15, c=k>>5, q=(k>>3)&3, j=k&7
//   bf16 idx = (w*32+c)*512 + 128*q + 8*r + j     (per-slot size 65536 bf16 = 32768 u32)
// Reader (wave w, chunk c, lane): contiguous 16B at u32 idx (w*32+c)*256 + 4*lane.

__global__ __launch_bounds__(NTHR, 1)
void lstm_kernel(const float* __restrict__ xf,
                 const float* __restrict__ h0,
                 const float* __restrict__ Wx,
                 const float* __restrict__ Wh,
                 const float* __restrict__ bias,
                 float* __restrict__ out,
                 u16* __restrict__ x_hi,   // ws: 64 MiB bf16 plane
                 u16* __restrict__ x_lo,   // ws: 64 MiB
                 u32* __restrict__ hslot,  // ws: 2 slots x 32768 u32 (fragment order, packed bf16 pairs)
                 u32* __restrict__ flags)  // ws: 256 u32, contiguous (16 cache lines)
{
  extern __shared__ char smem[];
  short* sWxh = (short*)smem;               // [16][KPX]
  short* sWxl = sWxh + 16 * KPX;
  short* sWhh = sWxl + 16 * KPX;
  short* sWhl = sWhh + 16 * KPX;
  float* accb   = (float*)(sWhl + 16 * KPX); // [64][17]  (stride 17: gate reads <=2-way banks)
  float* hstage = accb + 64 * 17;            // [64][4]

  const int blk  = blockIdx.x;
  const int tid  = threadIdx.x;
  const int lane = tid & 63;
  const int wave = tid >> 6;
  const int gid  = blk * NTHR + tid;
  cg::grid_group grid = cg::this_grid();

  // ================= phase 0: conversions + zero flags =================
  {
    const long NX = (long)NBATCH * TSTEPS * DDIM;
    for (long i = (long)gid * 4; i < NX; i += (long)NBLK * NTHR * 4) {
      const float4 v = *(const float4*)(xf + i);
      ushort4 hi, lo;
      hi.x = bf_hi(v.x); lo.x = bf_hi(v.x - bf2f(hi.x));
      hi.y = bf_hi(v.y); lo.y = bf_hi(v.y - bf2f(hi.y));
      hi.z = bf_hi(v.z); lo.z = bf_hi(v.z - bf2f(hi.z));
      hi.w = bf_hi(v.w); lo.w = bf_hi(v.w - bf2f(hi.w));
      *(ushort4*)(x_hi + i) = hi;
      *(ushort4*)(x_lo + i) = lo;
    }
    // h0 -> slot0 fragment plane (bf16 hi only)
    for (int i = gid; i < NBATCH * HDIM; i += NBLK * NTHR) {
      const int n = i >> 10, k = i & 1023;
      const int w = n >> 4, r = n & 15, c = k >> 5, q = (k >> 3) & 3, j = k & 7;
      ((u16*)hslot)[(w * 32 + c) * 512 + 128 * q + 8 * r + j] = bf_hi(h0[i]);
    }
    if (gid < NBLK)
      __hip_atomic_store(&flags[gid], 0u, __ATOMIC_RELAXED, __HIP_MEMORY_SCOPE_AGENT);
  }

  // ================= weight slabs -> LDS (hi/lo split) =================
  for (int it = tid; it < DDIM * 4; it += NTHR) {
    const int k = it & 1023, g = it >> 10;
    const float4 wx = *(const float4*)(Wx + (size_t)k * ACOLS + g * HDIM + blk * HCB);
    const float4 wh = *(const float4*)(Wh + (size_t)k * ACOLS + g * HDIM + blk * HCB);
    const float* wxp = &wx.x;
    const float* whp = &wh.x;
    #pragma unroll
    for (int j = 0; j < 4; ++j) {
      const int col = g * 4 + j;
      const u16 xh = bf_hi(wxp[j]);
      sWxh[col * KPX + k] = (short)xh;
      sWxl[col * KPX + k] = (short)bf_hi(wxp[j] - bf2f(xh));
      const u16 hh = bf_hi(whp[j]);
      sWhh[col * KPX + k] = (short)hh;
      sWhl[col * KPX + k] = (short)bf_hi(whp[j] - bf2f(hh));
    }
  }

  // gate-thread constants: thread t -> (n = t>>2, hc = t&3)
  const int gn = tid >> 2;
  const int ghc = tid & 3;
  float bb[4];
  #pragma unroll
  for (int g = 0; g < 4; ++g) bb[g] = bias[g * HDIM + blk * HCB + ghc];
  float cst = 0.0f;

  // h-writer constants: thread t<64 owns batch row n=t, stores one u64 (4 packed bf16 = this
  // block's 4 h-cols). u32 pair (k0=blk*4 -> idx, idx+1) consecutive & 8B aligned (j0=4*(blk&1), even idx).
  int hw_q = 0;
  {
    const int k0 = blk * HCB;
    const int w2 = tid >> 4, r2 = tid & 15, c2 = k0 >> 5, q2 = (k0 >> 3) & 3, j0 = k0 & 7;
    hw_q = ((w2 * 32 + c2) * 256 + 64 * q2 + 4 * r2 + (j0 >> 1)) >> 1;
  }

  // MFMA lane geometry
  const int mrow = lane & 15;
  const int kq   = lane >> 4;
  const int n0   = wave * 16 + mrow;
  const u16* xh_row = x_hi + (size_t)n0 * (TSTEPS * DDIM) + 8 * kq;
  const u16* xl_row = x_lo + (size_t)n0 * (TSTEPS * DDIM) + 8 * kq;
  const short* bxh = sWxh + mrow * KPX + 8 * kq;
  const short* bxl = sWxl + mrow * KPX + 8 * kq;
  const short* bhh = sWhh + mrow * KPX + 8 * kq;
  const short* bhl = sWhl + mrow * KPX + 8 * kq;

  grid.sync();  // publishes x planes, h0 plane, zeroed flags (full fence once)

  for (int s = 0; s < TSTEPS; ++s) {
    f32x4 acc = {0.f, 0.f, 0.f, 0.f};

    // ---------- x-half: (xh+xl) @ (Wxh+Wxl), 3-term split; independent of h_s ----------
    {
      const u16* xh_p = xh_row + (size_t)s * DDIM;
      const u16* xl_p = xl_row + (size_t)s * DDIM;
      bf16x8 Ah[4], Al[4], Bh[4], Bl[4];
      #pragma unroll
      for (int p = 0; p < 4; ++p) {
        Ah[p] = *(const bf16x8*)(xh_p + p * 32);
        Al[p] = *(const bf16x8*)(xl_p + p * 32);
        Bh[p] = *(const bf16x8*)(bxh + p * 32);
        Bl[p] = *(const bf16x8*)(bxl + p * 32);
      }
      #pragma unroll
      for (int i = 0; i < 32; ++i) {
        const int sl = i & 3;
        acc = __builtin_amdgcn_mfma_f32_16x16x32_bf16(Ah[sl], Bh[sl], acc, 0, 0, 0);
        acc = __builtin_amdgcn_mfma_f32_16x16x32_bf16(Ah[sl], Bl[sl], acc, 0, 0, 0);
        acc = __builtin_amdgcn_mfma_f32_16x16x32_bf16(Al[sl], Bh[sl], acc, 0, 0, 0);
        if (i < 28) {
          Ah[sl] = *(const bf16x8*)(xh_p + (i + 4) * 32);
          Al[sl] = *(const bf16x8*)(xl_p + (i + 4) * 32);
          Bh[sl] = *(const bf16x8*)(bxh + (i + 4) * 32);
          Bl[sl] = *(const bf16x8*)(bxl + (i + 4) * 32);
        }
      }
    }

    // ---------- wait for h_s: wave-0-only poll (coherent), then agent-acquire ----------
    if (s > 0) {
      if (wave == 0) {
        const uint4* fp = reinterpret_cast<const uint4*>(flags) + lane;
        for (;;) {
          uint4 f;
          asm volatile("global_load_dwordx4 %0, %1, off sc0 sc1\n\ts_waitcnt vmcnt(0)"
                       : "=v"(f) : "v"(fp) : "memory");
          const bool ok = (f.x >= (u32)s) & (f.y >= (u32)s) & (f.z >= (u32)s) & (f.w >= (u32)s);
          if (__all(ok)) break;
          __builtin_amdgcn_s_sleep(2);
        }
        // acquire: invalidate CU L1 + XCD L2 clean lines so the cached h reads below
        // observe the slot data published at MALL (emits buffer_inv sc1 on gfx950).
        __builtin_amdgcn_fence(__ATOMIC_ACQUIRE, "agent");
      }
      __syncthreads();
    }

    // ---------- h-half: h_hi @ (Whh+Whl); CACHED loads -> per-XCD L2 multicast ----------
    {
      const uint4* hb = (const uint4*)(hslot + (size_t)(s & 1) * 32768);
      union AU { uint4 u; bf16x8 v; };
      AU A[32];
      #pragma unroll
      for (int p = 0; p < 32; ++p)
        A[p].u = hb[(wave * 32 + p) * 64 + lane];
      #pragma unroll
      for (int i = 0; i < 32; ++i) {
        acc = __builtin_amdgcn_mfma_f32_16x16x32_bf16(A[i].v, *(const bf16x8*)(bhh + i * 32), acc, 0, 0, 0);
        acc = __builtin_amdgcn_mfma_f32_16x16x32_bf16(A[i].v, *(const bf16x8*)(bhl + i * 32), acc, 0, 0, 0);
      }
    }

    // ---------- partials -> LDS (C/D: col=lane&15, row=(lane>>4)*4+reg) ----------
    #pragma unroll
    for (int r = 0; r < 4; ++r)
      accb[(wave * 16 + kq * 4 + r) * 17 + mrow] = acc[r];
    __syncthreads();

    // ---------- gates ----------
    float hv;
    {
      float av[4];
      #pragma unroll
      for (int g = 0; g < 4; ++g) av[g] = accb[gn * 17 + g * 4 + ghc] + bb[g];
      const float ig = 1.0f / (1.0f + __expf(-av[0]));
      const float fg = 1.0f / (1.0f + __expf(-av[1]));
      const float og = 1.0f / (1.0f + __expf(-av[2]));
      const float e2 = __expf(2.0f * av[3]);
      const float gg = (e2 - 1.0f) / (e2 + 1.0f);
      cst = fg * cst + ig * gg;
      const float e2c = __expf(2.0f * cst);
      hv = og * ((e2c - 1.0f) / (e2c + 1.0f));
      hstage[gn * 4 + ghc] = hv;
    }
    __syncthreads();

    // ---------- publish h_{s+1}: one u64 (4 packed bf16) per batch row, coherent stores ----------
    if (tid < 64) {
      const float4 h4 = *(const float4*)(hstage + tid * 4);
      const u32 p0 = (u32)bf_hi(h4.x) | ((u32)bf_hi(h4.y) << 16);
      const u32 p1 = (u32)bf_hi(h4.z) | ((u32)bf_hi(h4.w) << 16);
      const u64 pk = (u64)p0 | ((u64)p1 << 32);
      u64* hdst = (u64*)(hslot + (size_t)((s + 1) & 1) * 32768) + hw_q;
      __hip_atomic_store(hdst, pk, __ATOMIC_RELAXED, __HIP_MEMORY_SCOPE_AGENT);
    }
    asm volatile("s_waitcnt vmcnt(0)" ::: "memory");  // own h-stores at coherence point
    __syncthreads();                                   // all 64 storers drained
    if (tid == 0)
      __hip_atomic_store(&flags[blk], (u32)(s + 1), __ATOMIC_RELAXED, __HIP_MEMORY_SCOPE_AGENT);
    // out store after the flag: off the critical path, drains during next step
    out[(size_t)gn * (TSTEPS * HDIM) + (size_t)s * HDIM + blk * HCB + ghc] = hv;
  }
}

extern "C" void kernel_launch(void* const* d_in, const int* in_sizes, int n_in,
                              void* d_out, int out_size, void* d_ws, size_t ws_size,
                              hipStream_t stream) {
  const float* x  = (const float*)d_in[0];
  const float* h0 = (const float*)d_in[1];
  const float* Wx = (const float*)d_in[2];
  const float* Wh = (const float*)d_in[3];
  const float* b  = (const float*)d_in[4];
  float* out = (float*)d_out;

  const size_t XPL = (size_t)NBATCH * TSTEPS * DDIM * 2;  // 64 MiB per plane
  u16* x_hi  = (u16*)d_ws;
  u16* x_lo  = (u16*)((char*)d_ws + XPL);
  u32* hslot = (u32*)((char*)d_ws + 2 * XPL);             // 2 x 128 KiB
  u32* flags = (u32*)((char*)d_ws + 2 * XPL + 2 * 65536 * 2);  // 1024 B (within old cnt footprint)

  const size_t smem = (size_t)(4 * 16 * KPX * 2) + (64 * 17 + 64 * 4) * sizeof(float); // 137472 B
  hipError_t e1 = hipFuncSetAttribute((const void*)lstm_kernel,
                                      hipFuncAttributeMaxDynamicSharedMemorySize, (int)smem);

  void* args[] = { (void*)&x, (void*)&h0, (void*)&Wx, (void*)&Wh, (void*)&b,
                   (void*)&out, (void*)&x_hi, (void*)&x_lo, (void*)&hslot, (void*)&flags };
  hipError_t e2 = hipLaunchCooperativeKernel((const void*)lstm_kernel, dim3(NBLK), dim3(NTHR),
                                             args, (unsigned)smem, stream);
  if (e1 != hipSuccess || e2 != hipSuccess)
    fprintf(stderr, "[lstm] setattr=%d launch=%d (%s)\n", (int)e1, (int)e2, hipGetErrorString(e2));
}

// Round 5
// 9722.376 us; speedup vs baseline: 1.1710x; 1.1710x over previous
//
#include <hip/hip_runtime.h>
#include <hip/hip_bf16.h>
#include <hip/hip_cooperative_groups.h>
#include <cstdio>

namespace cg = cooperative_groups;

#define NBATCH 64
#define TSTEPS 512
#define DDIM   1024
#define HDIM   1024
#define ACOLS  4096
#define NBLK   256
#define NTHR   256
#define HCB    4        // h-cols per block -> 16 a-cols
#define KPX    1032     // LDS k-stride: start-bank groups land 8 lanes / 4-bank group (balanced for b128)

typedef __attribute__((ext_vector_type(8))) short bf16x8;
typedef __attribute__((ext_vector_type(4))) float f32x4;
typedef unsigned int  u32;
typedef unsigned short u16;
typedef unsigned long long u64;

__device__ __forceinline__ u16 bf_hi(float f) { __hip_bfloat16 h = __float2bfloat16(f); return *(u16*)&h; }
__device__ __forceinline__ float bf2f(u16 u)  { __hip_bfloat16 h = *(__hip_bfloat16*)&u; return __bfloat162float(h); }

// h fragment-plane indexing: element (row n, col k) ->
//   w=n>>4, r=n&15, c=k>>5, q=(k>>3)&3, j=k&7
//   bf16 idx = (w*32+c)*512 + 128*q + 8*r + j     (per-slot size 65536 bf16 = 32768 u32)
// Reader (wave w, chunk c, lane): contiguous 16B at u32 idx (w*32+c)*256 + 4*lane.

__global__ __launch_bounds__(NTHR, 1)
void lstm_kernel(const float* __restrict__ xf,
                 const float* __restrict__ h0,
                 const float* __restrict__ Wx,
                 const float* __restrict__ Wh,
                 const float* __restrict__ bias,
                 float* __restrict__ out,
                 u16* __restrict__ x_hi,   // ws: 64 MiB bf16 plane
                 u16* __restrict__ x_lo,   // ws: 64 MiB
                 u32* __restrict__ hslot,  // ws: 2 slots x 32768 u32 (fragment order, packed bf16 pairs)
                 u32* __restrict__ flags)  // ws: 256 u32, contiguous (16 cache lines)
{
  extern __shared__ char smem[];
  short* sWxh = (short*)smem;               // [16][KPX]
  short* sWxl = sWxh + 16 * KPX;
  short* sWhh = sWxl + 16 * KPX;
  short* sWhl = sWhh + 16 * KPX;
  float* accb   = (float*)(sWhl + 16 * KPX); // [64][17]  (stride 17: gate reads <=2-way banks)
  float* hstage = accb + 64 * 17;            // [64][4]

  const int blk  = blockIdx.x;
  const int tid  = threadIdx.x;
  const int lane = tid & 63;
  const int wave = tid >> 6;
  const int gid  = blk * NTHR + tid;
  cg::grid_group grid = cg::this_grid();

  // ================= phase 0: conversions + zero flags =================
  {
    const long NX = (long)NBATCH * TSTEPS * DDIM;
    for (long i = (long)gid * 4; i < NX; i += (long)NBLK * NTHR * 4) {
      const float4 v = *(const float4*)(xf + i);
      ushort4 hi, lo;
      hi.x = bf_hi(v.x); lo.x = bf_hi(v.x - bf2f(hi.x));
      hi.y = bf_hi(v.y); lo.y = bf_hi(v.y - bf2f(hi.y));
      hi.z = bf_hi(v.z); lo.z = bf_hi(v.z - bf2f(hi.z));
      hi.w = bf_hi(v.w); lo.w = bf_hi(v.w - bf2f(hi.w));
      *(ushort4*)(x_hi + i) = hi;
      *(ushort4*)(x_lo + i) = lo;
    }
    // h0 -> slot0 fragment plane (bf16 hi only)
    for (int i = gid; i < NBATCH * HDIM; i += NBLK * NTHR) {
      const int n = i >> 10, k = i & 1023;
      const int w = n >> 4, r = n & 15, c = k >> 5, q = (k >> 3) & 3, j = k & 7;
      ((u16*)hslot)[(w * 32 + c) * 512 + 128 * q + 8 * r + j] = bf_hi(h0[i]);
    }
    if (gid < NBLK)
      __hip_atomic_store(&flags[gid], 0u, __ATOMIC_RELAXED, __HIP_MEMORY_SCOPE_AGENT);
  }

  // ================= weight slabs -> LDS (hi/lo split) =================
  for (int it = tid; it < DDIM * 4; it += NTHR) {
    const int k = it & 1023, g = it >> 10;
    const float4 wx = *(const float4*)(Wx + (size_t)k * ACOLS + g * HDIM + blk * HCB);
    const float4 wh = *(const float4*)(Wh + (size_t)k * ACOLS + g * HDIM + blk * HCB);
    const float* wxp = &wx.x;
    const float* whp = &wh.x;
    #pragma unroll
    for (int j = 0; j < 4; ++j) {
      const int col = g * 4 + j;
      const u16 xh = bf_hi(wxp[j]);
      sWxh[col * KPX + k] = (short)xh;
      sWxl[col * KPX + k] = (short)bf_hi(wxp[j] - bf2f(xh));
      const u16 hh = bf_hi(whp[j]);
      sWhh[col * KPX + k] = (short)hh;
      sWhl[col * KPX + k] = (short)bf_hi(whp[j] - bf2f(hh));
    }
  }

  // gate-thread constants: thread t -> (n = t>>2, hc = t&3)
  const int gn = tid >> 2;
  const int ghc = tid & 3;
  float bb[4];
  #pragma unroll
  for (int g = 0; g < 4; ++g) bb[g] = bias[g * HDIM + blk * HCB + ghc];
  float cst = 0.0f;

  // h-writer constants: thread t<64 owns batch row n=t, stores one u64 (4 packed bf16 = this
  // block's 4 h-cols). u32 pair (k0=blk*4 -> idx, idx+1) consecutive & 8B aligned (j0=4*(blk&1), even idx).
  int hw_q = 0;
  {
    const int k0 = blk * HCB;
    const int w2 = tid >> 4, r2 = tid & 15, c2 = k0 >> 5, q2 = (k0 >> 3) & 3, j0 = k0 & 7;
    hw_q = ((w2 * 32 + c2) * 256 + 64 * q2 + 4 * r2 + (j0 >> 1)) >> 1;
  }

  // MFMA lane geometry
  const int mrow = lane & 15;
  const int kq   = lane >> 4;
  const int n0   = wave * 16 + mrow;
  const u16* xh_row = x_hi + (size_t)n0 * (TSTEPS * DDIM) + 8 * kq;
  const u16* xl_row = x_lo + (size_t)n0 * (TSTEPS * DDIM) + 8 * kq;
  const short* bxh = sWxh + mrow * KPX + 8 * kq;
  const short* bxl = sWxl + mrow * KPX + 8 * kq;
  const short* bhh = sWhh + mrow * KPX + 8 * kq;
  const short* bhl = sWhl + mrow * KPX + 8 * kq;

  // x-half GEMM for timestep s: (xh+xl) @ (Wxh+Wxl), 3-term split — identical op order to before
  auto xgemm = [&](int s) -> f32x4 {
    const u16* xh_p = xh_row + (size_t)s * DDIM;
    const u16* xl_p = xl_row + (size_t)s * DDIM;
    f32x4 a = {0.f, 0.f, 0.f, 0.f};
    bf16x8 Ah[4], Al[4], Bh[4], Bl[4];
    #pragma unroll
    for (int p = 0; p < 4; ++p) {
      Ah[p] = *(const bf16x8*)(xh_p + p * 32);
      Al[p] = *(const bf16x8*)(xl_p + p * 32);
      Bh[p] = *(const bf16x8*)(bxh + p * 32);
      Bl[p] = *(const bf16x8*)(bxl + p * 32);
    }
    #pragma unroll
    for (int i = 0; i < 32; ++i) {
      const int sl = i & 3;
      a = __builtin_amdgcn_mfma_f32_16x16x32_bf16(Ah[sl], Bh[sl], a, 0, 0, 0);
      a = __builtin_amdgcn_mfma_f32_16x16x32_bf16(Ah[sl], Bl[sl], a, 0, 0, 0);
      a = __builtin_amdgcn_mfma_f32_16x16x32_bf16(Al[sl], Bh[sl], a, 0, 0, 0);
      if (i < 28) {
        Ah[sl] = *(const bf16x8*)(xh_p + (i + 4) * 32);
        Al[sl] = *(const bf16x8*)(xl_p + (i + 4) * 32);
        Bh[sl] = *(const bf16x8*)(bxh + (i + 4) * 32);
        Bl[sl] = *(const bf16x8*)(bxl + (i + 4) * 32);
      }
    }
    return a;
  };

  grid.sync();  // publishes x planes, h0 plane, zeroed flags (full fence once)

  // prologue: x-half for step 0 (h0 is already available, no poll needed at s=0)
  f32x4 acc_x = xgemm(0);

  for (int s = 0; s < TSTEPS; ++s) {
    // ---------- wait for h_s: wave-0-only poll, 64 lanes x dwordx4 over 16 lines ----------
    if (s > 0) {
      if (wave == 0) {
        const uint4* fp = reinterpret_cast<const uint4*>(flags) + lane;
        for (;;) {
          uint4 f;
          asm volatile("global_load_dwordx4 %0, %1, off sc0 sc1\n\ts_waitcnt vmcnt(0)"
                       : "=v"(f) : "v"(fp) : "memory");
          const bool ok = (f.x >= (u32)s) & (f.y >= (u32)s) & (f.z >= (u32)s) & (f.w >= (u32)s);
          if (__all(ok)) break;
          __builtin_amdgcn_s_sleep(2);
        }
      }
      __syncthreads();
    }

    // ---------- h-half: seed with precomputed x partials, forced bypass burst ----------
    f32x4 acc = acc_x;
    {
      u32* hsrc = hslot + (size_t)(s & 1) * 32768;
      const uint4* hb = (const uint4*)(hsrc + 4 * lane);   // 16B-aligned
      union AU { uint4 u; bf16x8 v; };
      AU A[32];
      #pragma unroll
      for (int p = 0; p < 32; ++p) {
        const uint4* hp = hb + (wave * 32 + p) * 64;       // (w*32+p)*256 u32 = *64 uint4
        asm volatile("global_load_dwordx4 %0, %1, off sc0 sc1"
                     : "=v"(A[p].u) : "v"(hp));
      }
      asm volatile("s_waitcnt vmcnt(0)" ::: "memory");
      __builtin_amdgcn_sched_barrier(0);                   // rule #18: MFMAs must not hoist past the wait
      #pragma unroll
      for (int i = 0; i < 32; ++i) {
        acc = __builtin_amdgcn_mfma_f32_16x16x32_bf16(A[i].v, *(const bf16x8*)(bhh + i * 32), acc, 0, 0, 0);
        acc = __builtin_amdgcn_mfma_f32_16x16x32_bf16(A[i].v, *(const bf16x8*)(bhl + i * 32), acc, 0, 0, 0);
      }
    }

    // ---------- partials -> LDS (C/D: col=lane&15, row=(lane>>4)*4+reg) ----------
    #pragma unroll
    for (int r = 0; r < 4; ++r)
      accb[(wave * 16 + kq * 4 + r) * 17 + mrow] = acc[r];
    __syncthreads();

    // ---------- gates ----------
    float hv;
    {
      float av[4];
      #pragma unroll
      for (int g = 0; g < 4; ++g) av[g] = accb[gn * 17 + g * 4 + ghc] + bb[g];
      const float ig = 1.0f / (1.0f + __expf(-av[0]));
      const float fg = 1.0f / (1.0f + __expf(-av[1]));
      const float og = 1.0f / (1.0f + __expf(-av[2]));
      const float e2 = __expf(2.0f * av[3]);
      const float gg = (e2 - 1.0f) / (e2 + 1.0f);
      cst = fg * cst + ig * gg;
      const float e2c = __expf(2.0f * cst);
      hv = og * ((e2c - 1.0f) / (e2c + 1.0f));
      hstage[gn * 4 + ghc] = hv;
    }
    __syncthreads();

    // ---------- publish h_{s+1}: one u64 (4 packed bf16) per batch row ----------
    if (tid < 64) {
      const float4 h4 = *(const float4*)(hstage + tid * 4);
      const u32 p0 = (u32)bf_hi(h4.x) | ((u32)bf_hi(h4.y) << 16);
      const u32 p1 = (u32)bf_hi(h4.z) | ((u32)bf_hi(h4.w) << 16);
      const u64 pk = (u64)p0 | ((u64)p1 << 32);
      u64* hdst = (u64*)(hslot + (size_t)((s + 1) & 1) * 32768) + hw_q;
      __hip_atomic_store(hdst, pk, __ATOMIC_RELAXED, __HIP_MEMORY_SCOPE_AGENT);
    }
    asm volatile("s_waitcnt vmcnt(0)" ::: "memory");  // own h-stores at coherence point
    __syncthreads();                                   // all 64 storers drained
    if (tid == 0)
      __hip_atomic_store(&flags[blk], (u32)(s + 1), __ATOMIC_RELAXED, __HIP_MEMORY_SCOPE_AGENT);

    // ---------- off-critical-path tail: out store + next step's x-half ----------
    out[(size_t)gn * (TSTEPS * HDIM) + (size_t)s * HDIM + blk * HCB + ghc] = hv;
    if (s + 1 < TSTEPS)
      acc_x = xgemm(s + 1);   // runs in the shadow of other blocks' publish/detect
  }
}

extern "C" void kernel_launch(void* const* d_in, const int* in_sizes, int n_in,
                              void* d_out, int out_size, void* d_ws, size_t ws_size,
                              hipStream_t stream) {
  const float* x  = (const float*)d_in[0];
  const float* h0 = (const float*)d_in[1];
  const float* Wx = (const float*)d_in[2];
  const float* Wh = (const float*)d_in[3];
  const float* b  = (const float*)d_in[4];
  float* out = (float*)d_out;

  const size_t XPL = (size_t)NBATCH * TSTEPS * DDIM * 2;  // 64 MiB per plane
  u16* x_hi  = (u16*)d_ws;
  u16* x_lo  = (u16*)((char*)d_ws + XPL);
  u32* hslot = (u32*)((char*)d_ws + 2 * XPL);             // 2 x 128 KiB
  u32* flags = (u32*)((char*)d_ws + 2 * XPL + 2 * 65536 * 2);  // 1024 B (within old cnt footprint)

  const size_t smem = (size_t)(4 * 16 * KPX * 2) + (64 * 17 + 64 * 4) * sizeof(float); // 137472 B
  hipError_t e1 = hipFuncSetAttribute((const void*)lstm_kernel,
                                      hipFuncAttributeMaxDynamicSharedMemorySize, (int)smem);

  void* args[] = { (void*)&x, (void*)&h0, (void*)&Wx, (void*)&Wh, (void*)&b,
                   (void*)&out, (void*)&x_hi, (void*)&x_lo, (void*)&hslot, (void*)&flags };
  hipError_t e2 = hipLaunchCooperativeKernel((const void*)lstm_kernel, dim3(NBLK), dim3(NTHR),
                                             args, (unsigned)smem, stream);
  if (e1 != hipSuccess || e2 != hipSuccess)
    fprintf(stderr, "[lstm] setattr=%d launch=%d (%s)\n", (int)e1, (int)e2, hipGetErrorString(e2));
}